// Round 4
// baseline (898.436 us; speedup 1.0000x reference)
//
#include <hip/hip_runtime.h>

// GCN 2-layer: N=100000, F=128 -> H=16 (relu) -> C=40, E=3200000.
// R3 -> R4: drop the CSR sort (k_bucket's random 4B cross-XCD writes cost
// 194MB HBM writeback for a 12.8MB buffer). Back to edge-parallel atomic
// scatter, but: (a) packed v2f32 atomics halve the atomic op count
// (R2 measured op-rate-bound at ~306 G-ops/s); (b) rows pre-scaled by
// dinv[src] so the scatter needs zero per-edge dinv gathers:
//   agg[n] = dinv[n]*( sum_e vs[s] + vs[n] ),  vs = dinv*v
// with the trailing dinv[n] folded into the next consumer.
//
// Pipeline (fp32):
//  k_zero/k_count : cnt = in-degree (int atomics)
//  k_dinv         : dinv = rsqrt(1+cnt)
//  k_gemm1        : vs1 = dinv*(x@W1) ; A1 = vs1 (self-loop init)
//  k_scatter      : A1[dst] += vs1[src]           (8 pk2-atomics/edge)
//  k_mid          : r = relu(dinv*A1+b1); vs2 = dinv*r; A2 = vs2
//  k_scatter      : A2[dst] += vs2[src]
//  k_out          : out = (dinv*A2)@W2 + b2

#define N_NODES 100000
#define F_IN    128
#define H_MID   16
#define C_OUT   40
#define N_EDGES 3200000

typedef float v2f __attribute__((ext_vector_type(2)));

__device__ __forceinline__ void atomic_pk_add_f32x2(float* p, float a, float b) {
#if __has_builtin(__builtin_amdgcn_flat_atomic_fadd_v2f32)
    v2f v; v.x = a; v.y = b;
    __builtin_amdgcn_flat_atomic_fadd_v2f32((v2f*)p, v);
#else
    atomicAdd(p, a);
    atomicAdd(p + 1, b);
#endif
}

__global__ void k_zero(int* __restrict__ cnt) {
    int i = blockIdx.x * 256 + threadIdx.x;
    if (i < N_NODES) cnt[i] = 0;
}

__global__ void k_count(const int* __restrict__ dst, int* __restrict__ cnt) {
    int e = blockIdx.x * 256 + threadIdx.x;
    if (e < N_EDGES) atomicAdd(&cnt[dst[e]], 1);
}

__global__ void k_dinv(const int* __restrict__ cnt, float* __restrict__ dinv) {
    int i = blockIdx.x * 256 + threadIdx.x;
    if (i < N_NODES) dinv[i] = rsqrtf(1.0f + (float)cnt[i]);   // +1 = self loop
}

// vs1 = dinv*(x@W1), A1 init = vs1. 16 nodes x 16 feats per 256-thread block.
__global__ void __launch_bounds__(256) k_gemm1(
    const float* __restrict__ x, const float* __restrict__ W1,
    const float* __restrict__ dinv,
    float* __restrict__ vs1, float* __restrict__ A1) {
    __shared__ float w[F_IN * H_MID];   // 8 KB
    __shared__ float xs[16 * 132];      // padded rows
    int t = threadIdx.x;
    for (int i = t; i < F_IN * H_MID; i += 256) w[i] = W1[i];
    int tile = blockIdx.x;              // 6250 tiles, exact
    const float4* xg = (const float4*)(x + (size_t)tile * 16 * F_IN);
    float4* xs4 = (float4*)xs;          // row stride 33 float4
    for (int i = t; i < 512; i += 256) {
        int r = i >> 5, c4 = i & 31;
        xs4[r * 33 + c4] = xg[r * 32 + c4];
    }
    __syncthreads();
    int node = t >> 4, j = t & 15;
    const float* xr = xs + node * 132;
    float acc = 0.f;
#pragma unroll 8
    for (int k = 0; k < F_IN; ++k) acc += xr[k] * w[k * H_MID + j];
    int g = tile * 16 + node;
    float v = acc * dinv[g];
    vs1[(size_t)g * H_MID + j] = v;
    A1[(size_t)g * H_MID + j]  = v;     // self-loop term as init
}

// A[dst] += vs[src] : 8 lanes per edge, float2 (packed atomic) per lane.
__global__ void k_scatter(const int* __restrict__ src, const int* __restrict__ dst,
                          const float* __restrict__ vs, float* __restrict__ A) {
    unsigned tid = blockIdx.x * 256 + threadIdx.x;
    unsigned e = tid >> 3;
    int j2 = tid & 7;
    if (e < N_EDGES) {
        int s = src[e], d = dst[e];
        const float2* row = (const float2*)(vs + (size_t)s * H_MID);
        float2 v = row[j2];             // 8 lanes -> one contiguous 64B row
        atomic_pk_add_f32x2(&A[(size_t)d * H_MID + 2 * j2], v.x, v.y);
    }
}

// r = relu(dinv*A1 + b1); vs2 = dinv*r; A2 init = vs2.
__global__ void k_mid(const float* __restrict__ A1, const float* __restrict__ b1,
                      const float* __restrict__ dinv,
                      float* __restrict__ vs2, float* __restrict__ A2) {
    int i = blockIdx.x * 256 + threadIdx.x;          // over N*H = 1.6M
    if (i < N_NODES * H_MID) {
        float dn = dinv[i >> 4];
        float r = fmaxf(dn * A1[i] + b1[i & 15], 0.f);
        float v = dn * r;
        vs2[i] = v;
        A2[i]  = v;
    }
}

// out = (dinv*A2)@W2 + b2 : 16 nodes/block x 40 classes = 640 threads.
__global__ void __launch_bounds__(640) k_out(
    const float* __restrict__ A2, const float* __restrict__ W2,
    const float* __restrict__ b2, const float* __restrict__ dinv,
    float* __restrict__ out) {
    __shared__ float w2[H_MID * C_OUT];  // 640
    __shared__ float r[16 * 17];         // padded
    int t = threadIdx.x;
    if (t < H_MID * C_OUT) w2[t] = W2[t];
    int tile = blockIdx.x;
    if (t < 256) {
        int node = t >> 4;
        r[node * 17 + (t & 15)] = dinv[tile * 16 + node] * A2[(size_t)tile * 256 + t];
    }
    __syncthreads();
    int node = t / C_OUT, c = t % C_OUT;
    float acc = 0.f;
#pragma unroll
    for (int j = 0; j < H_MID; ++j) acc += r[node * 17 + j] * w2[j * C_OUT + c];
    out[(size_t)(tile * 16 + node) * C_OUT + c] = b2[c] + acc;
}

extern "C" void kernel_launch(void* const* d_in, const int* in_sizes, int n_in,
                              void* d_out, int out_size, void* d_ws, size_t ws_size,
                              hipStream_t stream) {
    const float* x  = (const float*)d_in[0];
    const int*   ei = (const int*)d_in[1];     // [2, E]: row 0 = src, row 1 = dst
    const float* W1 = (const float*)d_in[2];
    const float* b1 = (const float*)d_in[3];
    const float* W2 = (const float*)d_in[4];
    const float* b2 = (const float*)d_in[5];
    float* out = (float*)d_out;

    const int* src = ei;
    const int* dst = ei + N_EDGES;

    // ws (4B units): cnt[100352] | dinv[100352] | vs1[1.6M] | A1[1.6M] |
    //                vs2[1.6M] | A2[1.6M]   ~= 26.4 MB
    int*   cnt  = (int*)d_ws;
    float* dinv = (float*)(cnt + 100352);
    float* vs1  = dinv + 100352;
    float* A1   = vs1 + (size_t)N_NODES * H_MID;
    float* vs2  = A1 + (size_t)N_NODES * H_MID;
    float* A2   = vs2 + (size_t)N_NODES * H_MID;

    const int B = 256;
    k_zero <<<(N_NODES + B - 1) / B, B, 0, stream>>>(cnt);
    k_count<<<(N_EDGES + B - 1) / B, B, 0, stream>>>(dst, cnt);
    k_dinv <<<(N_NODES + B - 1) / B, B, 0, stream>>>(cnt, dinv);
    k_gemm1<<<N_NODES / 16, 256, 0, stream>>>(x, W1, dinv, vs1, A1);
    {
        long long threads = (long long)N_EDGES * 8;   // 25.6M
        k_scatter<<<(unsigned)((threads + B - 1) / B), B, 0, stream>>>(src, dst, vs1, A1);
    }
    k_mid<<<(N_NODES * H_MID + B - 1) / B, B, 0, stream>>>(A1, b1, dinv, vs2, A2);
    {
        long long threads = (long long)N_EDGES * 8;   // 25.6M
        k_scatter<<<(unsigned)((threads + B - 1) / B), B, 0, stream>>>(src, dst, vs2, A2);
    }
    k_out<<<N_NODES / 16, 640, 0, stream>>>(A2, W2, b2, dinv, out);
}